// Round 1
// baseline (6281.276 us; speedup 1.0000x reference)
//
#include <hip/hip_runtime.h>
#include <math.h>

#define T_TASKS 64
#define NS 75
#define NW 5
#define NTOT 375
#define NQ 150
#define DIM 4096
#define QP_ITERS 15
#define SIGMA 0.1f
#define CREG 0.1f
#define NBLK_QP 320

// workspace layout (float offsets). K padded 76x76 (5776/task).
// W in register-tile layout: per (b,w) 6400 floats, [(m*5+n)*256 + tid].
// vbuf (1310720) aliases the W region (W dead after QP loop).
// Barrier counter hides in the tv pad (element r=75 of tv slot 0 is never
// touched: tv writes/reads are guarded r<75).
// Total 2,520,064 floats = 10.1 MB (unchanged from previous version).
#define OFF_K   0u
#define OFF_W   369664u
#define OFF_Z   2417664u
#define OFF_S   2441664u
#define OFF_LAM 2465664u
#define OFF_NU  2489664u
#define OFF_TV  2494464u   // 320*80
#define OFF_BAR (OFF_TV + 75u)

// ------------------------------------------------------------ init state + Kg
// Kg: zero everywhere except pad diagonal (row==col>=75 -> 1). gram_atomic
// then accumulates K into the 75x75 block; factor adds (1 + D) on the diag.
__global__ void init_kernel(float* __restrict__ Kg, float* __restrict__ z,
                            float* __restrict__ s, float* __restrict__ lam,
                            float* __restrict__ nu, int* __restrict__ bar) {
    int idx = blockIdx.x * 256 + threadIdx.x;
    if (idx == 0) bar[0] = 0;
    if (idx < T_TASKS * 5776) {
        int rc = idx % 5776;
        int row = rc / 76, col = rc % 76;
        Kg[idx] = (row == col && row >= 75) ? 1.f : 0.f;
    }
    if (idx < T_TASKS * NTOT) { z[idx] = 0.f; s[idx] = 1.f; lam[idx] = 1.f; }
    if (idx < T_TASKS * NS) nu[idx] = 0.f;
}

// ------------------------------------------- K partial over a 256-wide d-chunk
// 16 chunks x 64 tasks = 1024 blocks (3 blocks/CU by LDS) -> latency hidden.
// Partials reduced via device-scope atomicAdd into Kg (zero-initialized).
__global__ __launch_bounds__(256) void gram_atomic(const float* __restrict__ support,
                                                   float* __restrict__ Kg) {
    int qd = blockIdx.x, b = blockIdx.y;
    __shared__ __align__(16) float Ss[80 * 132];
    int tid = threadIdx.x;
    int tx = tid & 15, ty = tid >> 4;
    float acc[5][5];
#pragma unroll
    for (int u = 0; u < 5; u++)
#pragma unroll
        for (int v = 0; v < 5; v++) acc[u][v] = 0.f;
    const float* sb = support + (size_t)b * NS * DIM + qd * 256;
    for (int cc = 0; cc < 2; cc++) {
        __syncthreads();
        for (int idx = tid; idx < 80 * 32; idx += 256) {
            int r = idx >> 5, d4 = idx & 31;
            float4 v = make_float4(0.f, 0.f, 0.f, 0.f);
            if (r < 75) v = *(const float4*)&sb[(size_t)r * DIM + cc * 128 + d4 * 4];
            *(float4*)&Ss[r * 132 + d4 * 4] = v;
        }
        __syncthreads();
        for (int d4 = 0; d4 < 32; d4++) {
            float4 av[5], bv[5];
#pragma unroll
            for (int u = 0; u < 5; u++) av[u] = *(const float4*)&Ss[(ty * 5 + u) * 132 + d4 * 4];
#pragma unroll
            for (int v = 0; v < 5; v++) bv[v] = *(const float4*)&Ss[(tx * 5 + v) * 132 + d4 * 4];
#pragma unroll
            for (int u = 0; u < 5; u++)
#pragma unroll
                for (int v = 0; v < 5; v++)
                    acc[u][v] += av[u].x * bv[v].x + av[u].y * bv[v].y +
                                 av[u].z * bv[v].z + av[u].w * bv[v].w;
        }
    }
    float* Ko = Kg + (size_t)b * 5776;
#pragma unroll
    for (int u = 0; u < 5; u++) {
        int row = ty * 5 + u;
#pragma unroll
        for (int v = 0; v < 5; v++) {
            int col = tx * 5 + v;
            if (row < 75 && col < 75) atomicAdd(&Ko[row * 76 + col], acc[u][v]);
        }
    }
}

// --------------- register-resident Gauss-Jordan inverse of 80x80 (pad>=75 I).
// Thread (ty,tx) owns rows {ty+16m} x cols {tx+16n} in M[5][5] (VGPRs).
// Per step: pivot row/col broadcast through double-buffered LDS (one barrier
// per k), rank-1 update in registers. Pivots k<75 only.
__device__ __forceinline__ void reg_gj80(float (&M)[5][5],
                                         float (*prow)[80], float (*fcol)[80],
                                         int tx, int ty) {
    for (int k = 0; k < 75; k++) {
        int bf = k & 1;
        if (ty == (k & 15)) {
#pragma unroll
            for (int m = 0; m < 5; m++) {
                if (ty + 16 * m == k) {
#pragma unroll
                    for (int n = 0; n < 5; n++) prow[bf][tx + 16 * n] = M[m][n];
                }
            }
        }
        if (tx == (k & 15)) {
#pragma unroll
            for (int n = 0; n < 5; n++) {
                if (tx + 16 * n == k) {
#pragma unroll
                    for (int m = 0; m < 5; m++) fcol[bf][ty + 16 * m] = M[m][n];
                }
            }
        }
        __syncthreads();
        float pinv = 1.f / prow[bf][k];
        float pv[5], fv[5], ps[5];
#pragma unroll
        for (int n = 0; n < 5; n++) {
            pv[n] = prow[bf][tx + 16 * n];
            ps[n] = pv[n] * pinv;
        }
#pragma unroll
        for (int m = 0; m < 5; m++) {
            int r = ty + 16 * m;
            float f = fcol[bf][r] * pinv;
            fv[m] = (r == k) ? 0.f : f;
        }
#pragma unroll
        for (int m = 0; m < 5; m++) {
            int r = ty + 16 * m;
            bool rk = (r == k);
#pragma unroll
            for (int n = 0; n < 5; n++) {
                int c = tx + 16 * n;
                float val = M[m][n] - fv[m] * pv[n];
                val = rk ? ps[n] : val;
                val = (c == k) ? (rk ? pinv : -fv[m]) : val;
                M[m][n] = val;
            }
        }
    }
}

// ----------------------------------------------------- monotone grid barrier
// Counter only increases; barrier p complete <=> cnt >= NBLK_QP*p. AGENT-scope
// acq_rel atomics provide cross-XCD visibility (release: L2 writeback on
// arrival; acquire: cache inv on the spin load). All 320 blocks are
// co-resident: __launch_bounds__(256,2) caps VGPR<=256 -> >=2 blocks/CU.
__device__ __forceinline__ void grid_barrier(int* bar, int& phase) {
    __syncthreads();
    phase++;
    if (threadIdx.x == 0) {
        __hip_atomic_fetch_add(bar, 1, __ATOMIC_ACQ_REL, __HIP_MEMORY_SCOPE_AGENT);
        while (__hip_atomic_load(bar, __ATOMIC_ACQUIRE, __HIP_MEMORY_SCOPE_AGENT)
               < NBLK_QP * phase)
            __builtin_amdgcn_s_sleep(2);
    }
    __syncthreads();
}

// ------------------------------------- fused QP loop: 15 iterations in ONE
// dispatch. Block bw: b=bw/5, w=bw%5. Phase A (all blocks): per-(b,w)
// residuals, H_w = K+I+D_w, W = H^-1 via reg-GJ, W/t -> global. Phase B
// (w==0 blocks): S = sum_w W_w, S^-1 via reg-GJ, dnu, dz/ds/dlam + step.
__global__ __launch_bounds__(256, 2) void qp_loop_kernel(
        const float* __restrict__ Kg, const int* __restrict__ labels,
        float* __restrict__ zg, float* __restrict__ sg,
        float* __restrict__ lamg, float* __restrict__ nug,
        float* __restrict__ Wg, float* __restrict__ tvg,
        int* __restrict__ bar) {
    int bw = blockIdx.x;
    int b = bw / NW, w = bw - b * NW;
    int tid = threadIdx.x;
    int tx = tid & 15, ty = tid >> 4;

    __shared__ float prow[2][80], fcol[2][80];
    __shared__ float zw[80], r1w[80], Dv[80], swv[80], lwv[80], nuwv[80];
    __shared__ int labv[80];
    __shared__ float mred[4], ared[4];
    __shared__ __align__(16) float rhs[80];
    __shared__ __align__(16) float dnu[80];

    const float* Kt = Kg + (size_t)b * 5776;
    float* Wo = Wg + (size_t)(b * NW + w) * 6400;
    const float* Wb = Wg + (size_t)b * NW * 6400;
    int phase = 0;

    for (int it = 0; it < QP_ITERS; it++) {
        // ============================ factor phase (all 320 blocks) =========
        {
            float M[5][5];
#pragma unroll
            for (int m = 0; m < 5; m++) {
                int r = ty + 16 * m;
#pragma unroll
                for (int n = 0; n < 5; n++) {
                    int c = tx + 16 * n;
                    M[m][n] = (r < 76 && c < 76) ? Kt[r * 76 + c] : ((r == c) ? 1.f : 0.f);
                }
            }
            if (tid < 80) {
                float zv = 0.f, sv = 1.f, lv = 0.f, nv = 0.f; int lb = -1;
                if (tid < 75) {
                    zv = zg[b * NTOT + tid * NW + w];
                    sv = sg[b * NTOT + tid * NW + w];
                    lv = lamg[b * NTOT + tid * NW + w];
                    nv = nug[b * NS + tid];
                    lb = labels[b * NS + tid];
                }
                zw[tid] = zv; swv[tid] = sv; lwv[tid] = lv; nuwv[tid] = nv; labv[tid] = lb;
            }
            float part = 0.f;
            for (int idx = tid; idx < NTOT; idx += 256)
                part += lamg[b * NTOT + idx] * sg[b * NTOT + idx];
#pragma unroll
            for (int off = 32; off > 0; off >>= 1) part += __shfl_xor(part, off, 64);
            if ((tid & 63) == 0) mred[tid >> 6] = part;
            __syncthreads();
            float mu = (mred[0] + mred[1] + mred[2] + mred[3]) * (1.f / (float)NTOT);

            // gz = K z (row dots via register tile + tx-reduction)
            float gp[5];
#pragma unroll
            for (int m = 0; m < 5; m++) {
                float a = 0.f;
#pragma unroll
                for (int n = 0; n < 5; n++) a += M[m][n] * zw[tx + 16 * n];
                gp[m] = a;
            }
#pragma unroll
            for (int off = 1; off < 16; off <<= 1)
#pragma unroll
                for (int m = 0; m < 5; m++) gp[m] += __shfl_xor(gp[m], off, 64);
            if (tx == 0) {
#pragma unroll
                for (int m = 0; m < 5; m++) {
                    int r = ty + 16 * m;
                    float val = 0.f, dv = 0.f;
                    if (r < 75) {
                        float sv = swv[r], lv = lwv[r], zv = zw[r];
                        float e = (labv[r] == w) ? -1.f : 0.f;
                        float h = (labv[r] == w) ? CREG : 0.f;
                        float rz = gp[m] + zv + e + lv + nuwv[r];
                        float rs = zv + sv - h;
                        val = -rz - (lv * rs - lv * sv + SIGMA * mu) / sv;
                        dv = lv / sv;
                    }
                    r1w[r] = val; Dv[r] = dv;
                }
            }
            __syncthreads();
            if (tx == ty) {
#pragma unroll
                for (int m = 0; m < 5; m++) {
                    int r = ty + 16 * m;
                    if (r < 75) M[m][m] += 1.f + Dv[r];
                }
            }
            // (no barrier needed: registers private; GJ's internal barrier orders LDS)

            reg_gj80(M, prow, fcol, tx, ty);

            // W out, tile layout: fully coalesced
#pragma unroll
            for (int m = 0; m < 5; m++)
#pragma unroll
                for (int n = 0; n < 5; n++)
                    Wo[(m * 5 + n) * 256 + tid] = M[m][n];

            // t = W r1
            float tp[5];
#pragma unroll
            for (int m = 0; m < 5; m++) {
                float a = 0.f;
#pragma unroll
                for (int n = 0; n < 5; n++) a += M[m][n] * r1w[tx + 16 * n];
                tp[m] = a;
            }
#pragma unroll
            for (int off = 1; off < 16; off <<= 1)
#pragma unroll
                for (int m = 0; m < 5; m++) tp[m] += __shfl_xor(tp[m], off, 64);
            if (tx == 0) {
#pragma unroll
                for (int m = 0; m < 5; m++) {
                    int r = ty + 16 * m;
                    if (r < 75) tvg[(b * NW + w) * 80 + r] = tp[m];
                }
            }
        }
        grid_barrier(bar, phase);

        // ============================ schur phase (w==0 blocks) =============
        if (w == 0) {
            float M[5][5];
#pragma unroll
            for (int m = 0; m < 5; m++)
#pragma unroll
                for (int n = 0; n < 5; n++) {
                    float a = 0.f;
#pragma unroll
                    for (int ww = 0; ww < 5; ww++)
                        a += Wb[ww * 6400 + (m * 5 + n) * 256 + tid];
                    M[m][n] = a;
                }
            if (tid < 80) {
                float rv = 0.f;
                if (tid < 75) {
#pragma unroll
                    for (int ww = 0; ww < 5; ww++)
                        rv += zg[b * NTOT + tid * NW + ww] + tvg[(b * NW + ww) * 80 + tid];
                }
                rhs[tid] = rv;
            }
            float part = 0.f;
            for (int idx = tid; idx < NTOT; idx += 256)
                part += lamg[b * NTOT + idx] * sg[b * NTOT + idx];
#pragma unroll
            for (int off = 32; off > 0; off >>= 1) part += __shfl_xor(part, off, 64);
            if ((tid & 63) == 0) mred[tid >> 6] = part;
            __syncthreads();
            float mu = (mred[0] + mred[1] + mred[2] + mred[3]) * (1.f / (float)NTOT);

            reg_gj80(M, prow, fcol, tx, ty);   // M = S^{-1}

            // dnu = Sinv * rhs
            float tp[5];
#pragma unroll
            for (int m = 0; m < 5; m++) {
                float a = 0.f;
#pragma unroll
                for (int n = 0; n < 5; n++) a += M[m][n] * rhs[tx + 16 * n];
                tp[m] = a;
            }
#pragma unroll
            for (int off = 1; off < 16; off <<= 1)
#pragma unroll
                for (int m = 0; m < 5; m++) tp[m] += __shfl_xor(tp[m], off, 64);
            if (tx == 0) {
#pragma unroll
                for (int m = 0; m < 5; m++) dnu[ty + 16 * m] = tp[m];
            }
            __syncthreads();

            // dz/ds/dlam + ratio; entries c = tid, tid+256
            float rat = INFINITY;
            float dzv[2], dsv[2], dlv[2], zlv[2], slv[2], llv[2];
#pragma unroll
            for (int pass = 0; pass < 2; pass++) {
                int c = tid + 256 * pass;
                dzv[pass] = 0.f; dsv[pass] = 0.f; dlv[pass] = 0.f;
                zlv[pass] = 0.f; slv[pass] = 1.f; llv[pass] = 0.f;
                if (c < NTOT) {
                    int i = c / 5, ww = c - (c / 5) * 5;
                    int mi = i >> 4, tyi = i & 15;
                    const float* Wr = Wb + ww * 6400 + mi * 5 * 256 + tyi * 16;
                    const float4* dn4 = (const float4*)dnu;
                    float acc = 0.f;
#pragma unroll
                    for (int n = 0; n < 5; n++) {
                        const float4* w4 = (const float4*)(Wr + n * 256);
#pragma unroll
                        for (int q = 0; q < 4; q++) {
                            float4 x = w4[q], y = dn4[4 * n + q];
                            acc += x.x * y.x + x.y * y.y + x.z * y.z + x.w * y.w;
                        }
                    }
                    float tvl = tvg[(b * NW + ww) * 80 + i];
                    float zl = zg[b * NTOT + c], sl = sg[b * NTOT + c], ll = lamg[b * NTOT + c];
                    float dz_t = tvl - acc;
                    int lb = labels[b * NS + i];
                    float h = (lb == ww) ? CREG : 0.f;
                    float rs = zl + sl - h;
                    float ds_t = -rs - dz_t;
                    float dl_t = (ll * dz_t + ll * rs - ll * sl + SIGMA * mu) / sl;
                    zlv[pass] = zl; slv[pass] = sl; llv[pass] = ll;
                    dzv[pass] = dz_t; dsv[pass] = ds_t; dlv[pass] = dl_t;
                    float r1 = (ds_t < 0.f) ? (-sl / ds_t) : INFINITY;
                    float r2 = (dl_t < 0.f) ? (-ll / dl_t) : INFINITY;
                    rat = fminf(rat, fminf(r1, r2));
                }
            }
#pragma unroll
            for (int off = 32; off > 0; off >>= 1) rat = fminf(rat, __shfl_xor(rat, off, 64));
            if ((tid & 63) == 0) ared[tid >> 6] = rat;
            __syncthreads();
            float alpha = fminf(1.f, 0.99f * fminf(fminf(ared[0], ared[1]), fminf(ared[2], ared[3])));
#pragma unroll
            for (int pass = 0; pass < 2; pass++) {
                int c = tid + 256 * pass;
                if (c < NTOT) {
                    zg[b * NTOT + c]   = zlv[pass] + alpha * dzv[pass];
                    sg[b * NTOT + c]   = slv[pass] + alpha * dsv[pass];
                    lamg[b * NTOT + c] = llv[pass] + alpha * dlv[pass];
                }
            }
            if (tid < 75) nug[b * NS + tid] += alpha * dnu[tid];
        }
        grid_barrier(bar, phase);
    }
}

// ------------------------------ v[b,w,:] = sum_s z[b,s,w] * support[b,s,:]
__global__ __launch_bounds__(256) void v_kernel(const float* __restrict__ support,
                                                const float* __restrict__ z,
                                                float* __restrict__ vbuf) {
    int dc = blockIdx.x, b = blockIdx.y;
    __shared__ float zs[NTOT];
    int tid = threadIdx.x;
    for (int idx = tid; idx < NTOT; idx += 256) zs[idx] = z[b * NTOT + idx];
    __syncthreads();
    int d = dc * 256 + tid;
    float acc[5] = {0.f, 0.f, 0.f, 0.f, 0.f};
    const float* sb = support + (size_t)b * NS * DIM + d;
    for (int ss = 0; ss < NS; ss++) {
        float svv = sb[(size_t)ss * DIM];
#pragma unroll
        for (int w = 0; w < 5; w++) acc[w] += svv * zs[ss * 5 + w];
    }
#pragma unroll
    for (int w = 0; w < 5; w++) vbuf[(size_t)(b * NW + w) * DIM + d] = acc[w];
}

// -------------------- logits[b,q,w] = sum_d query[b,q,d] * v[b,w,d]
__global__ __launch_bounds__(256) void logits_kernel(const float* __restrict__ query,
                                                     const float* __restrict__ vbuf,
                                                     float* __restrict__ out) {
    int qt = blockIdx.x, b = blockIdx.y;
    __shared__ __align__(16) float vs[5 * 1028];
    int tid = threadIdx.x;
    int lane = tid & 63, wid = tid >> 6;
    float acc[8][5];
#pragma unroll
    for (int r = 0; r < 8; r++)
#pragma unroll
        for (int w = 0; w < 5; w++) acc[r][w] = 0.f;

    for (int c = 0; c < 4; c++) {
        __syncthreads();
        for (int idx = tid; idx < 5120; idx += 256) {
            int w = idx >> 10, dd = idx & 1023;
            vs[w * 1028 + dd] = vbuf[(size_t)(b * NW + w) * DIM + c * 1024 + dd];
        }
        __syncthreads();
#pragma unroll
        for (int ri = 0; ri < 8; ri++) {
            int r = wid + ri * 4;
            if (r < 30) {
                int q = qt * 30 + r;
                const float* qp = query + (size_t)(b * NQ + q) * DIM + c * 1024;
#pragma unroll
                for (int j = 0; j < 4; j++) {
                    int d = lane * 4 + j * 256;
                    float4 qv = *(const float4*)(qp + d);
#pragma unroll
                    for (int w = 0; w < 5; w++) {
                        float4 vv = *(const float4*)(&vs[w * 1028 + d]);
                        acc[ri][w] += qv.x * vv.x + qv.y * vv.y + qv.z * vv.z + qv.w * vv.w;
                    }
                }
            }
        }
    }
#pragma unroll
    for (int ri = 0; ri < 8; ri++) {
        int r = wid + ri * 4;
#pragma unroll
        for (int w = 0; w < 5; w++) {
            float v = acc[ri][w];
            for (int off = 32; off > 0; off >>= 1) v += __shfl_xor(v, off, 64);
            if (r < 30 && lane == 0)
                out[(size_t)(b * NQ + qt * 30 + r) * NW + w] = v;
        }
    }
}

// ---------------------------------------------------------------------------
extern "C" void kernel_launch(void* const* d_in, const int* in_sizes, int n_in,
                              void* d_out, int out_size, void* d_ws, size_t ws_size,
                              hipStream_t stream) {
    const float* query   = (const float*)d_in[0];
    const float* support = (const float*)d_in[1];
    const int*   labels  = (const int*)d_in[2];
    float* out = (float*)d_out;
    float* ws  = (float*)d_ws;

    float* Kg   = ws + OFF_K;
    float* Wg   = ws + OFF_W;
    float* vbuf = ws + OFF_W;   // alias (W dead after QP loop)
    float* z    = ws + OFF_Z;
    float* s    = ws + OFF_S;
    float* lam  = ws + OFF_LAM;
    float* nu   = ws + OFF_NU;
    float* tv   = ws + OFF_TV;
    int*   bar  = (int*)(ws + OFF_BAR);

    init_kernel<<<(T_TASKS * 5776 + 255) / 256, 256, 0, stream>>>(Kg, z, s, lam, nu, bar);
    gram_atomic<<<dim3(16, T_TASKS), 256, 0, stream>>>(support, Kg);
    qp_loop_kernel<<<NBLK_QP, 256, 0, stream>>>(Kg, labels, z, s, lam, nu, Wg, tv, bar);
    v_kernel<<<dim3(16, T_TASKS), 256, 0, stream>>>(support, z, vbuf);
    logits_kernel<<<dim3(5, T_TASKS), 256, 0, stream>>>(query, vbuf, out);
}

// Round 2
// 2146.278 us; speedup vs baseline: 2.9266x; 2.9266x over previous
//
#include <hip/hip_runtime.h>
#include <math.h>

#define T_TASKS 64
#define NS 75
#define NW 5
#define NTOT 375
#define NQ 150
#define DIM 4096
#define QP_ITERS 15
#define SIGMA 0.1f
#define CREG 0.1f
#define NBLK_QP 320

// workspace layout (float offsets). K padded 76x76 (5776/task).
// W in register-tile layout: per (b,w) 6400 floats, [(m*5+n)*256 + tid].
// vbuf (1310720) aliases the W region (W dead after QP loop).
// Per-task arrival counters hide in the tv pads: tv slot (b*5+0), element
// r=75 (tv reads/writes are guarded r<75). Counter stride = 400 floats
// = 1600 B (no cache-line sharing between tasks).
// Total 2,520,064 floats = 10.1 MB (unchanged).
#define OFF_K   0u
#define OFF_W   369664u
#define OFF_Z   2417664u
#define OFF_S   2441664u
#define OFF_LAM 2465664u
#define OFF_NU  2489664u
#define OFF_TV  2494464u   // 320*80
#define CNT_OFF(b) ((b) * 400 + 75)

// ------------------------------------------------------------ init state + Kg
// Kg: zero everywhere except pad diagonal (row==col>=75 -> 1). gram_atomic
// accumulates K into the 75x75 block; factor adds (1 + D) on the diag.
__global__ void init_kernel(float* __restrict__ Kg, float* __restrict__ z,
                            float* __restrict__ s, float* __restrict__ lam,
                            float* __restrict__ nu, int* __restrict__ cnt) {
    int idx = blockIdx.x * 256 + threadIdx.x;
    if (idx < T_TASKS) cnt[CNT_OFF(idx)] = 0;
    if (idx < T_TASKS * 5776) {
        int rc = idx % 5776;
        int row = rc / 76, col = rc % 76;
        Kg[idx] = (row == col && row >= 75) ? 1.f : 0.f;
    }
    if (idx < T_TASKS * NTOT) { z[idx] = 0.f; s[idx] = 1.f; lam[idx] = 1.f; }
    if (idx < T_TASKS * NS) nu[idx] = 0.f;
}

// ------------------------------------------- K partial over a 256-wide d-chunk
// 16 chunks x 64 tasks = 1024 blocks (3 blocks/CU by LDS) -> latency hidden.
// Partials reduced via device-scope atomicAdd into Kg (zero-initialized).
__global__ __launch_bounds__(256) void gram_atomic(const float* __restrict__ support,
                                                   float* __restrict__ Kg) {
    int qd = blockIdx.x, b = blockIdx.y;
    __shared__ __align__(16) float Ss[80 * 132];
    int tid = threadIdx.x;
    int tx = tid & 15, ty = tid >> 4;
    float acc[5][5];
#pragma unroll
    for (int u = 0; u < 5; u++)
#pragma unroll
        for (int v = 0; v < 5; v++) acc[u][v] = 0.f;
    const float* sb = support + (size_t)b * NS * DIM + qd * 256;
    for (int cc = 0; cc < 2; cc++) {
        __syncthreads();
        for (int idx = tid; idx < 80 * 32; idx += 256) {
            int r = idx >> 5, d4 = idx & 31;
            float4 v = make_float4(0.f, 0.f, 0.f, 0.f);
            if (r < 75) v = *(const float4*)&sb[(size_t)r * DIM + cc * 128 + d4 * 4];
            *(float4*)&Ss[r * 132 + d4 * 4] = v;
        }
        __syncthreads();
        for (int d4 = 0; d4 < 32; d4++) {
            float4 av[5], bv[5];
#pragma unroll
            for (int u = 0; u < 5; u++) av[u] = *(const float4*)&Ss[(ty * 5 + u) * 132 + d4 * 4];
#pragma unroll
            for (int v = 0; v < 5; v++) bv[v] = *(const float4*)&Ss[(tx * 5 + v) * 132 + d4 * 4];
#pragma unroll
            for (int u = 0; u < 5; u++)
#pragma unroll
                for (int v = 0; v < 5; v++)
                    acc[u][v] += av[u].x * bv[v].x + av[u].y * bv[v].y +
                                 av[u].z * bv[v].z + av[u].w * bv[v].w;
        }
    }
    float* Ko = Kg + (size_t)b * 5776;
#pragma unroll
    for (int u = 0; u < 5; u++) {
        int row = ty * 5 + u;
#pragma unroll
        for (int v = 0; v < 5; v++) {
            int col = tx * 5 + v;
            if (row < 75 && col < 75) atomicAdd(&Ko[row * 76 + col], acc[u][v]);
        }
    }
}

// --------------- register-resident Gauss-Jordan inverse of 80x80 (pad>=75 I).
// Thread (ty,tx) owns rows {ty+16m} x cols {tx+16n} in M[5][5] (VGPRs).
// Per step: pivot row/col broadcast through double-buffered LDS (one barrier
// per k), rank-1 update in registers. Pivots k<75 only.
__device__ __forceinline__ void reg_gj80(float (&M)[5][5],
                                         float (*prow)[80], float (*fcol)[80],
                                         int tx, int ty) {
    for (int k = 0; k < 75; k++) {
        int bf = k & 1;
        if (ty == (k & 15)) {
#pragma unroll
            for (int m = 0; m < 5; m++) {
                if (ty + 16 * m == k) {
#pragma unroll
                    for (int n = 0; n < 5; n++) prow[bf][tx + 16 * n] = M[m][n];
                }
            }
        }
        if (tx == (k & 15)) {
#pragma unroll
            for (int n = 0; n < 5; n++) {
                if (tx + 16 * n == k) {
#pragma unroll
                    for (int m = 0; m < 5; m++) fcol[bf][ty + 16 * m] = M[m][n];
                }
            }
        }
        __syncthreads();
        float pinv = 1.f / prow[bf][k];
        float pv[5], fv[5], ps[5];
#pragma unroll
        for (int n = 0; n < 5; n++) {
            pv[n] = prow[bf][tx + 16 * n];
            ps[n] = pv[n] * pinv;
        }
#pragma unroll
        for (int m = 0; m < 5; m++) {
            int r = ty + 16 * m;
            float f = fcol[bf][r] * pinv;
            fv[m] = (r == k) ? 0.f : f;
        }
#pragma unroll
        for (int m = 0; m < 5; m++) {
            int r = ty + 16 * m;
            bool rk = (r == k);
#pragma unroll
            for (int n = 0; n < 5; n++) {
                int c = tx + 16 * n;
                float val = M[m][n] - fv[m] * pv[n];
                val = rk ? ps[n] : val;
                val = (c == k) ? (rk ? pinv : -fv[m]) : val;
                M[m][n] = val;
            }
        }
    }
}

// ------------------------------------- one QP iteration per launch.
// Block bw: b=bw/5, w=bw%5. All blocks: per-(b,w) residuals, H_w = K+I+D_w,
// W = H^-1 via reg-GJ, W/t -> global, release-increment task counter.
// w==0 blocks then spin (RELAXED polls -> no cache invalidation; single
// ACQUIRE after exit) until all 5 sibling blocks arrived, then do the Schur
// phase: S = sum_w W_w, S^-1 via reg-GJ, dnu, dz/ds/dlam + step.
// Deadlock-free: only w==0 blocks wait, and only on non-waiting blocks.
__global__ __launch_bounds__(256) void qp_iter_kernel(
        const float* __restrict__ Kg, const int* __restrict__ labels,
        float* __restrict__ zg, float* __restrict__ sg,
        float* __restrict__ lamg, float* __restrict__ nug,
        float* __restrict__ Wg, float* __restrict__ tvg,
        int* __restrict__ cnt, int it) {
    int bw = blockIdx.x;
    int b = bw / NW, w = bw - b * NW;
    int tid = threadIdx.x;
    int tx = tid & 15, ty = tid >> 4;

    __shared__ float prow[2][80], fcol[2][80];
    __shared__ float zw[80], r1w[80], Dv[80], swv[80], lwv[80], nuwv[80];
    __shared__ int labv[80];
    __shared__ float mred[4], ared[4];
    __shared__ __align__(16) float rhs[80];
    __shared__ __align__(16) float dnu[80];

    const float* Kt = Kg + (size_t)b * 5776;
    float* Wo = Wg + (size_t)(b * NW + w) * 6400;
    const float* Wb = Wg + (size_t)b * NW * 6400;

    // ============================ factor phase (all 320 blocks) =============
    float M[5][5];
#pragma unroll
    for (int m = 0; m < 5; m++) {
        int r = ty + 16 * m;
#pragma unroll
        for (int n = 0; n < 5; n++) {
            int c = tx + 16 * n;
            M[m][n] = (r < 76 && c < 76) ? Kt[r * 76 + c] : ((r == c) ? 1.f : 0.f);
        }
    }
    if (tid < 80) {
        float zv = 0.f, sv = 1.f, lv = 0.f, nv = 0.f; int lb = -1;
        if (tid < 75) {
            zv = zg[b * NTOT + tid * NW + w];
            sv = sg[b * NTOT + tid * NW + w];
            lv = lamg[b * NTOT + tid * NW + w];
            nv = nug[b * NS + tid];
            lb = labels[b * NS + tid];
        }
        zw[tid] = zv; swv[tid] = sv; lwv[tid] = lv; nuwv[tid] = nv; labv[tid] = lb;
    }
    {
        float part = 0.f;
        for (int idx = tid; idx < NTOT; idx += 256)
            part += lamg[b * NTOT + idx] * sg[b * NTOT + idx];
#pragma unroll
        for (int off = 32; off > 0; off >>= 1) part += __shfl_xor(part, off, 64);
        if ((tid & 63) == 0) mred[tid >> 6] = part;
    }
    __syncthreads();
    float mu = (mred[0] + mred[1] + mred[2] + mred[3]) * (1.f / (float)NTOT);

    // gz = K z (row dots via register tile + tx-reduction)
    {
        float gp[5];
#pragma unroll
        for (int m = 0; m < 5; m++) {
            float a = 0.f;
#pragma unroll
            for (int n = 0; n < 5; n++) a += M[m][n] * zw[tx + 16 * n];
            gp[m] = a;
        }
#pragma unroll
        for (int off = 1; off < 16; off <<= 1)
#pragma unroll
            for (int m = 0; m < 5; m++) gp[m] += __shfl_xor(gp[m], off, 64);
        if (tx == 0) {
#pragma unroll
            for (int m = 0; m < 5; m++) {
                int r = ty + 16 * m;
                float val = 0.f, dv = 0.f;
                if (r < 75) {
                    float sv = swv[r], lv = lwv[r], zv = zw[r];
                    float e = (labv[r] == w) ? -1.f : 0.f;
                    float h = (labv[r] == w) ? CREG : 0.f;
                    float rz = gp[m] + zv + e + lv + nuwv[r];
                    float rs = zv + sv - h;
                    val = -rz - (lv * rs - lv * sv + SIGMA * mu) / sv;
                    dv = lv / sv;
                }
                r1w[r] = val; Dv[r] = dv;
            }
        }
    }
    __syncthreads();
    if (tx == ty) {
#pragma unroll
        for (int m = 0; m < 5; m++) {
            int r = ty + 16 * m;
            if (r < 75) M[m][m] += 1.f + Dv[r];
        }
    }
    // (no barrier needed: registers private; GJ's internal barrier orders LDS)

    reg_gj80(M, prow, fcol, tx, ty);

    // W out, tile layout: fully coalesced
#pragma unroll
    for (int m = 0; m < 5; m++)
#pragma unroll
        for (int n = 0; n < 5; n++)
            Wo[(m * 5 + n) * 256 + tid] = M[m][n];

    // t = W r1
    {
        float tp[5];
#pragma unroll
        for (int m = 0; m < 5; m++) {
            float a = 0.f;
#pragma unroll
            for (int n = 0; n < 5; n++) a += M[m][n] * r1w[tx + 16 * n];
            tp[m] = a;
        }
#pragma unroll
        for (int off = 1; off < 16; off <<= 1)
#pragma unroll
            for (int m = 0; m < 5; m++) tp[m] += __shfl_xor(tp[m], off, 64);
        if (tx == 0) {
#pragma unroll
            for (int m = 0; m < 5; m++) {
                int r = ty + 16 * m;
                if (r < 75) tvg[(b * NW + w) * 80 + r] = tp[m];
            }
        }
    }

    // arrival: all this block's global stores drained (syncthreads waits
    // vmcnt(0) per thread), then one release-increment (L2 writeback).
    __syncthreads();
    if (tid == 0)
        __hip_atomic_fetch_add(&cnt[CNT_OFF(b)], 1, __ATOMIC_RELEASE,
                               __HIP_MEMORY_SCOPE_AGENT);
    if (w != 0) return;

    // ============================ schur phase (w==0 blocks) =================
    if (tid == 0) {
        int target = 5 * (it + 1);   // counters are monotone across the 15 launches
        while (__hip_atomic_load(&cnt[CNT_OFF(b)], __ATOMIC_RELAXED,
                                 __HIP_MEMORY_SCOPE_AGENT) < target)
            __builtin_amdgcn_s_sleep(8);
        (void)__hip_atomic_load(&cnt[CNT_OFF(b)], __ATOMIC_ACQUIRE,
                                __HIP_MEMORY_SCOPE_AGENT);
    }
    __syncthreads();

    // S = sum_w W_w; own W_0 is still in M's registers.
#pragma unroll
    for (int m = 0; m < 5; m++)
#pragma unroll
        for (int n = 0; n < 5; n++) {
            float a = M[m][n];
#pragma unroll
            for (int ww = 1; ww < 5; ww++)
                a += Wb[ww * 6400 + (m * 5 + n) * 256 + tid];
            M[m][n] = a;
        }
    if (tid < 80) {
        float rv = 0.f;
        if (tid < 75) {
#pragma unroll
            for (int ww = 0; ww < 5; ww++)
                rv += zg[b * NTOT + tid * NW + ww] + tvg[(b * NW + ww) * 80 + tid];
        }
        rhs[tid] = rv;
    }
    __syncthreads();

    reg_gj80(M, prow, fcol, tx, ty);   // M = S^{-1}

    // dnu = Sinv * rhs
    {
        float tp[5];
#pragma unroll
        for (int m = 0; m < 5; m++) {
            float a = 0.f;
#pragma unroll
            for (int n = 0; n < 5; n++) a += M[m][n] * rhs[tx + 16 * n];
            tp[m] = a;
        }
#pragma unroll
        for (int off = 1; off < 16; off <<= 1)
#pragma unroll
            for (int m = 0; m < 5; m++) tp[m] += __shfl_xor(tp[m], off, 64);
        if (tx == 0) {
#pragma unroll
            for (int m = 0; m < 5; m++) dnu[ty + 16 * m] = tp[m];
        }
    }
    __syncthreads();

    // dz/ds/dlam + ratio; entries c = tid, tid+256
    float rat = INFINITY;
    float dzv[2], dsv[2], dlv[2], zlv[2], slv[2], llv[2];
#pragma unroll
    for (int pass = 0; pass < 2; pass++) {
        int c = tid + 256 * pass;
        dzv[pass] = 0.f; dsv[pass] = 0.f; dlv[pass] = 0.f;
        zlv[pass] = 0.f; slv[pass] = 1.f; llv[pass] = 0.f;
        if (c < NTOT) {
            int i = c / 5, ww = c - (c / 5) * 5;
            int mi = i >> 4, tyi = i & 15;
            const float* Wr = Wb + ww * 6400 + mi * 5 * 256 + tyi * 16;
            const float4* dn4 = (const float4*)dnu;
            float acc = 0.f;
#pragma unroll
            for (int n = 0; n < 5; n++) {
                const float4* w4 = (const float4*)(Wr + n * 256);
#pragma unroll
                for (int q = 0; q < 4; q++) {
                    float4 x = w4[q], y = dn4[4 * n + q];
                    acc += x.x * y.x + x.y * y.y + x.z * y.z + x.w * y.w;
                }
            }
            float tvl = tvg[(b * NW + ww) * 80 + i];
            float zl = zg[b * NTOT + c], sl = sg[b * NTOT + c], ll = lamg[b * NTOT + c];
            float dz_t = tvl - acc;
            int lb = labels[b * NS + i];
            float h = (lb == ww) ? CREG : 0.f;
            float rs = zl + sl - h;
            float ds_t = -rs - dz_t;
            float dl_t = (ll * dz_t + ll * rs - ll * sl + SIGMA * mu) / sl;
            zlv[pass] = zl; slv[pass] = sl; llv[pass] = ll;
            dzv[pass] = dz_t; dsv[pass] = ds_t; dlv[pass] = dl_t;
            float r1 = (ds_t < 0.f) ? (-sl / ds_t) : INFINITY;
            float r2 = (dl_t < 0.f) ? (-ll / dl_t) : INFINITY;
            rat = fminf(rat, fminf(r1, r2));
        }
    }
#pragma unroll
    for (int off = 32; off > 0; off >>= 1) rat = fminf(rat, __shfl_xor(rat, off, 64));
    if ((tid & 63) == 0) ared[tid >> 6] = rat;
    __syncthreads();
    float alpha = fminf(1.f, 0.99f * fminf(fminf(ared[0], ared[1]), fminf(ared[2], ared[3])));
#pragma unroll
    for (int pass = 0; pass < 2; pass++) {
        int c = tid + 256 * pass;
        if (c < NTOT) {
            zg[b * NTOT + c]   = zlv[pass] + alpha * dzv[pass];
            sg[b * NTOT + c]   = slv[pass] + alpha * dsv[pass];
            lamg[b * NTOT + c] = llv[pass] + alpha * dlv[pass];
        }
    }
    if (tid < 75) nug[b * NS + tid] += alpha * dnu[tid];
}

// ------------------------------ v[b,w,:] = sum_s z[b,s,w] * support[b,s,:]
__global__ __launch_bounds__(256) void v_kernel(const float* __restrict__ support,
                                                const float* __restrict__ z,
                                                float* __restrict__ vbuf) {
    int dc = blockIdx.x, b = blockIdx.y;
    __shared__ float zs[NTOT];
    int tid = threadIdx.x;
    for (int idx = tid; idx < NTOT; idx += 256) zs[idx] = z[b * NTOT + idx];
    __syncthreads();
    int d = dc * 256 + tid;
    float acc[5] = {0.f, 0.f, 0.f, 0.f, 0.f};
    const float* sb = support + (size_t)b * NS * DIM + d;
    for (int ss = 0; ss < NS; ss++) {
        float svv = sb[(size_t)ss * DIM];
#pragma unroll
        for (int w = 0; w < 5; w++) acc[w] += svv * zs[ss * 5 + w];
    }
#pragma unroll
    for (int w = 0; w < 5; w++) vbuf[(size_t)(b * NW + w) * DIM + d] = acc[w];
}

// -------------------- logits[b,q,w] = sum_d query[b,q,d] * v[b,w,d]
__global__ __launch_bounds__(256) void logits_kernel(const float* __restrict__ query,
                                                     const float* __restrict__ vbuf,
                                                     float* __restrict__ out) {
    int qt = blockIdx.x, b = blockIdx.y;
    __shared__ __align__(16) float vs[5 * 1028];
    int tid = threadIdx.x;
    int lane = tid & 63, wid = tid >> 6;
    float acc[8][5];
#pragma unroll
    for (int r = 0; r < 8; r++)
#pragma unroll
        for (int w = 0; w < 5; w++) acc[r][w] = 0.f;

    for (int c = 0; c < 4; c++) {
        __syncthreads();
        for (int idx = tid; idx < 5120; idx += 256) {
            int w = idx >> 10, dd = idx & 1023;
            vs[w * 1028 + dd] = vbuf[(size_t)(b * NW + w) * DIM + c * 1024 + dd];
        }
        __syncthreads();
#pragma unroll
        for (int ri = 0; ri < 8; ri++) {
            int r = wid + ri * 4;
            if (r < 30) {
                int q = qt * 30 + r;
                const float* qp = query + (size_t)(b * NQ + q) * DIM + c * 1024;
#pragma unroll
                for (int j = 0; j < 4; j++) {
                    int d = lane * 4 + j * 256;
                    float4 qv = *(const float4*)(qp + d);
#pragma unroll
                    for (int w = 0; w < 5; w++) {
                        float4 vv = *(const float4*)(&vs[w * 1028 + d]);
                        acc[ri][w] += qv.x * vv.x + qv.y * vv.y + qv.z * vv.z + qv.w * vv.w;
                    }
                }
            }
        }
    }
#pragma unroll
    for (int ri = 0; ri < 8; ri++) {
        int r = wid + ri * 4;
#pragma unroll
        for (int w = 0; w < 5; w++) {
            float v = acc[ri][w];
            for (int off = 32; off > 0; off >>= 1) v += __shfl_xor(v, off, 64);
            if (r < 30 && lane == 0)
                out[(size_t)(b * NQ + qt * 30 + r) * NW + w] = v;
        }
    }
}

// ---------------------------------------------------------------------------
extern "C" void kernel_launch(void* const* d_in, const int* in_sizes, int n_in,
                              void* d_out, int out_size, void* d_ws, size_t ws_size,
                              hipStream_t stream) {
    const float* query   = (const float*)d_in[0];
    const float* support = (const float*)d_in[1];
    const int*   labels  = (const int*)d_in[2];
    float* out = (float*)d_out;
    float* ws  = (float*)d_ws;

    float* Kg   = ws + OFF_K;
    float* Wg   = ws + OFF_W;
    float* vbuf = ws + OFF_W;   // alias (W dead after QP loop)
    float* z    = ws + OFF_Z;
    float* s    = ws + OFF_S;
    float* lam  = ws + OFF_LAM;
    float* nu   = ws + OFF_NU;
    float* tv   = ws + OFF_TV;
    int*   cnt  = (int*)(ws + OFF_TV);   // counters live in tv pads (r=75)

    init_kernel<<<(T_TASKS * 5776 + 255) / 256, 256, 0, stream>>>(Kg, z, s, lam, nu, cnt);
    gram_atomic<<<dim3(16, T_TASKS), 256, 0, stream>>>(support, Kg);
    for (int it = 0; it < QP_ITERS; it++)
        qp_iter_kernel<<<NBLK_QP, 256, 0, stream>>>(Kg, labels, z, s, lam, nu, Wg, tv, cnt, it);
    v_kernel<<<dim3(16, T_TASKS), 256, 0, stream>>>(support, z, vbuf);
    logits_kernel<<<dim3(5, T_TASKS), 256, 0, stream>>>(query, vbuf, out);
}